// Round 10
// baseline (171.083 us; speedup 1.0000x reference)
//
#include <hip/hip_runtime.h>

#define BH 64
#define S_ 4096
#define D_ 128
#define SCALE 0.25f  // 1/sqrt(n_heads=16)

typedef __attribute__((ext_vector_type(4))) short short4v;
typedef __attribute__((ext_vector_type(8))) short short8v;
typedef __attribute__((ext_vector_type(4))) float f32x4;

__device__ inline unsigned short f2bf(float x) {
  union { float f; unsigned u; } v; v.f = x;
  unsigned r = v.u + 0x7fff + ((v.u >> 16) & 1);
  return (unsigned short)(r >> 16);
}
__device__ inline short8v cat8(short4v a, short4v b) {
  short8v r;
  r[0] = a[0]; r[1] = a[1]; r[2] = a[2]; r[3] = a[3];
  r[4] = b[0]; r[5] = b[1]; r[6] = b[2]; r[7] = b[3];
  return r;
}
// Hardware transpose read (semantics verified rounds 2-9).
__device__ inline short4v tr16(unsigned addr) {
  short4v r;
  asm volatile("ds_read_b64_tr_b16 %0, %1" : "=v"(r) : "v"(addr));
  return r;
}
// Truncation-based hi/lo bf16 split of two floats, packed (elem0 in low 16).
__device__ inline void cvt_pair(float x0, float x1, unsigned& hi, unsigned& lo) {
  unsigned u0 = __float_as_uint(x0), u1 = __float_as_uint(x1);
  unsigned m0 = u0 & 0xffff0000u, m1 = u1 & 0xffff0000u;
  hi = m1 | (u0 >> 16);
  float l0 = x0 - __uint_as_float(m0);
  float l1 = x1 - __uint_as_float(m1);
  lo = (__float_as_uint(l1) & 0xffff0000u) | (__float_as_uint(l0) >> 16);
}

// ---------------------------------------------------------------------------
// Phase A: split-K QK^T, split-bf16 (hi/lo) 3-pass MFMA — pv-shaped grid.
// Grid (bh=64, ks=16, dh=2): 2048 blocks x 256 threads (4 waves), 3 blocks/CU.
// Block computes partial rows d in [dh*64, dh*64+64) x all 128 e, over 256 s.
// part[ks][bh][d][e] = SCALE * sum_s q[s][d]*k[s][e]
//
// LDS per buffer (24 KB): Qhi[32s x 64d] Qlo | Khi[32s x 128e] Klo, each in
// the 4x16-subtile layout (R6-verified tr16 mapping).  Double-buffered,
// ONE __syncthreads per step (see hazard audit below).
//
// Subtile layout, C cols: slot s(8B) -> id=s>>4; cb=id&(C/16-1); kg=id/(C/16);
//   row=kg*4+((s>>2)&3); col=cb*16+(s&3)*4.  tr16 lane addr:
//   (l>>4)*(4*C*2) + ((l&15)>>2)*32 + (l&3)*8 + kh*(16*C*2) + cb*128.
//
// Hazard audit (single barrier): step st writes buf[st&1] BEFORE the sync,
// reads it after.  Next write of buf[st&1] is at step st+2, which every wave
// reaches only after passing step st+1's sync; every wave's buf[st&1] reads
// (iter st) are lgkm-drained before its own MFMA(st), hence before it reaches
// sync(st+1).  Writes at st+1 target the OTHER buffer.  => safe.
// ---------------------------------------------------------------------------
#define QTILE_U 1024   // uints per 32x64 bf16 tile (4 KB)
#define KTILE_U 2048   // uints per 32x128 bf16 tile (8 KB)
#define BUFU 6144      // uints per buffer (Qhi Qlo Khi Klo = 24 KB)
#define BUFB 24576     // bytes per buffer

template <bool ATOMIC>
__global__ __launch_bounds__(256, 3) void qk_mfma(const float* __restrict__ q,
                                                  const float* __restrict__ k,
                                                  float* __restrict__ part) {
  constexpr int nsteps = 8;  // 256 s-rows per block, 32 per step
  const int bh = blockIdx.x;
  const int ks = blockIdx.y;
  const int dh = blockIdx.z;
  const float* qb = q + ((size_t)bh * S_ + ks * 256) * D_ + dh * 64;
  const float* kb = k + ((size_t)bh * S_ + ks * 256) * D_;

  __shared__ alignas(16) short lds[2 * 12288];  // 48 KB
  unsigned* baseU = (unsigned*)&lds[0];
  const unsigned base_b = (unsigned)(uintptr_t)&lds[0];

  const int tid = threadIdx.x;
  const int wv = tid >> 6, lane = tid & 63;
  const int wm = wv & 1;   // m-block: 32 d of this block's 64
  const int wn = wv >> 1;  // n-block: 64 e of 128

  f32x4 acc[2][4];
#pragma unroll
  for (int a = 0; a < 2; ++a)
#pragma unroll
    for (int b = 0; b < 4; ++b) acc[a][b] = (f32x4){0.f, 0.f, 0.f, 0.f};

  // load geometry (slot->row/col bijections for C=64 (Q) and C=128 (K))
  const int rq = ((tid >> 6) << 2) | ((tid >> 2) & 3);
  const int cq = (((tid >> 4) & 3) << 4) | ((tid & 3) << 2);
  const int rk = ((tid >> 7) << 2) | ((tid >> 2) & 3);
  const int ck = (((tid >> 4) & 7) << 4) | ((tid & 3) << 2);

  float4 qr[2], kr[4];
  auto load_step = [&](int st) {
    qr[0] = *(const float4*)(qb + (size_t)(st * 32 + rq) * D_ + cq);
    qr[1] = *(const float4*)(qb + (size_t)(st * 32 + rq + 16) * D_ + cq);
#pragma unroll
    for (int j = 0; j < 4; ++j)
      kr[j] = *(const float4*)(kb + (size_t)(st * 32 + rk + j * 8) * D_ + ck);
  };
  auto cvt_store = [&](int b) {
    unsigned* bufU = baseU + b * BUFU;
#pragma unroll
    for (int i = 0; i < 2; ++i) {   // Q slots t, t+256
      unsigned off = (unsigned)(tid + i * 256) * 2;
      unsigned h0, l0, h1, l1;
      cvt_pair(qr[i].x, qr[i].y, h0, l0);
      cvt_pair(qr[i].z, qr[i].w, h1, l1);
      *(uint2*)(bufU + off) = make_uint2(h0, h1);
      *(uint2*)(bufU + QTILE_U + off) = make_uint2(l0, l1);
    }
#pragma unroll
    for (int j = 0; j < 4; ++j) {   // K slots t + j*256
      unsigned off = (unsigned)(tid + j * 256) * 2;
      unsigned h0, l0, h1, l1;
      cvt_pair(kr[j].x, kr[j].y, h0, l0);
      cvt_pair(kr[j].z, kr[j].w, h1, l1);
      *(uint2*)(bufU + 2 * QTILE_U + off) = make_uint2(h0, h1);
      *(uint2*)(bufU + 2 * QTILE_U + KTILE_U + off) = make_uint2(l0, l1);
    }
  };

  // tr16 per-lane constants
  const unsigned lq = ((unsigned)(lane >> 4) << 9) |
                      ((unsigned)((lane & 15) >> 2) << 5) |
                      ((unsigned)(lane & 3) << 3);
  const unsigned lk = ((unsigned)(lane >> 4) << 10) |
                      ((unsigned)((lane & 15) >> 2) << 5) |
                      ((unsigned)(lane & 3) << 3);
  const unsigned aQ = base_b + lq;          // Qhi +0, Qlo +4096; kh*2048
  const unsigned aK = base_b + 8192 + lk;   // Khi +0, Klo +8192; kh*4096

  load_step(0);
  for (int st = 0; st < nsteps; ++st) {
    const int b = st & 1;
    cvt_store(b);
    if (st + 1 < nsteps) load_step(st + 1);
    __syncthreads();

    const unsigned bo = (unsigned)b * BUFB;
    short4v Bf[4][2][2];
#pragma unroll
    for (int bb = 0; bb < 4; ++bb) {
      unsigned cb = (unsigned)(wn * 4 + bb) << 7;
#pragma unroll
      for (int ver = 0; ver < 2; ++ver)
#pragma unroll
        for (int kh = 0; kh < 2; ++kh)
          Bf[bb][ver][kh] = tr16(aK + bo + ver * 8192 + kh * 4096 + cb);
    }
    short4v Af[2][2][2];
#pragma unroll
    for (int a = 0; a < 2; ++a) {
      unsigned cb = (unsigned)(wm * 2 + a) << 7;
#pragma unroll
      for (int ver = 0; ver < 2; ++ver)
#pragma unroll
        for (int kh = 0; kh < 2; ++kh)
          Af[a][ver][kh] = tr16(aQ + bo + ver * 4096 + kh * 2048 + cb);
    }
    asm volatile("s_waitcnt lgkmcnt(0)" ::: "memory");
    __builtin_amdgcn_sched_barrier(0);

#pragma unroll
    for (int a = 0; a < 2; ++a) {
      short8v ah = cat8(Af[a][0][0], Af[a][0][1]);
      short8v al = cat8(Af[a][1][0], Af[a][1][1]);
#pragma unroll
      for (int bb = 0; bb < 4; ++bb) {
        short8v bh_ = cat8(Bf[bb][0][0], Bf[bb][0][1]);
        short8v bl_ = cat8(Bf[bb][1][0], Bf[bb][1][1]);
        acc[a][bb] = __builtin_amdgcn_mfma_f32_16x16x32_bf16(ah, bh_, acc[a][bb], 0, 0, 0);
        acc[a][bb] = __builtin_amdgcn_mfma_f32_16x16x32_bf16(ah, bl_, acc[a][bb], 0, 0, 0);
        acc[a][bb] = __builtin_amdgcn_mfma_f32_16x16x32_bf16(al, bh_, acc[a][bb], 0, 0, 0);
      }
    }
  }

  // epilogue: D layout col=lane&15, row=(lane>>4)*4+reg ; d = dh*64 + local
  if (!ATOMIC) {
    float* dst = part + ((size_t)ks * BH + bh) * D_ * D_;
#pragma unroll
    for (int a = 0; a < 2; ++a)
#pragma unroll
      for (int bb = 0; bb < 4; ++bb) {
        int e = (wn * 4 + bb) * 16 + (lane & 15);
#pragma unroll
        for (int r = 0; r < 4; ++r) {
          int d = dh * 64 + (wm * 2 + a) * 16 + ((lane >> 4) << 2) + r;
          dst[(size_t)d * D_ + e] = acc[a][bb][r] * SCALE;
        }
      }
  } else {
    float* dst = part + (size_t)bh * D_ * D_;
#pragma unroll
    for (int a = 0; a < 2; ++a)
#pragma unroll
      for (int bb = 0; bb < 4; ++bb) {
        int e = (wn * 4 + bb) * 16 + (lane & 15);
#pragma unroll
        for (int r = 0; r < 4; ++r) {
          int d = dh * 64 + (wm * 2 + a) * 16 + ((lane >> 4) << 2) + r;
          atomicAdd(&dst[(size_t)d * D_ + e], acc[a][bb][r] * SCALE);
        }
      }
  }
}

// ---------------------------------------------------------------------------
// Phase B: combine partials + row softmax -> P as bf16 (linear [d][e])
// ---------------------------------------------------------------------------
template <int NKS>
__global__ __launch_bounds__(256) void softmax_k(const float* __restrict__ part,
                                                 short* __restrict__ Pg) {
  const int bh = blockIdx.x;
  const int wv = threadIdx.x >> 6, lane = threadIdx.x & 63;
  const size_t kstride = (size_t)BH * D_ * D_;
  const float* base = part + (size_t)bh * D_ * D_;
  short* dst = Pg + (size_t)bh * D_ * D_;
#pragma unroll
  for (int i = 0; i < 8; ++i) {
    int d = blockIdx.y * 32 + wv * 8 + i;
    float v0 = 0.f, v1 = 0.f;
    for (int ks2 = 0; ks2 < NKS; ++ks2) {
      const float* row = base + ks2 * kstride + (size_t)d * D_;
      v0 += row[lane];
      v1 += row[lane + 64];
    }
    float m = fmaxf(v0, v1);
#pragma unroll
    for (int off = 32; off; off >>= 1) m = fmaxf(m, __shfl_xor(m, off, 64));
    float e0 = __expf(v0 - m), e1 = __expf(v1 - m);
    float s = e0 + e1;
#pragma unroll
    for (int off = 32; off; off >>= 1) s += __shfl_xor(s, off, 64);
    float inv = 1.f / s;
    dst[(size_t)d * D_ + lane] = (short)f2bf(e0 * inv);
    dst[(size_t)d * D_ + lane + 64] = (short)f2bf(e1 * inv);
  }
}

// ---------------------------------------------------------------------------
// Phase C: out[d][s] = sum_e P[d][e] * v[s][e] — bf16 MFMA over contiguous e.
// ---------------------------------------------------------------------------
__global__ __launch_bounds__(256) void pv_mfma(const short* __restrict__ Pg,
                                               const float* __restrict__ v,
                                               float* __restrict__ out) {
  const int bh = blockIdx.x;
  const int s0 = blockIdx.y * 128;
  const float* vb = v + (size_t)bh * S_ * D_;
  __shared__ alignas(16) short P_lds[128 * 136];
  __shared__ alignas(16) short V_lds[128 * 36];
  const int tid = threadIdx.x;
  const int wv = tid >> 6, lane = tid & 63;

  const short* Pb = Pg + (size_t)bh * D_ * D_;
#pragma unroll
  for (int i = 0; i < 8; ++i) {
    int idx8 = tid + i * 256;
    int row = idx8 >> 4, c8 = idx8 & 15;
    short8v val = *(const short8v*)(Pb + row * 128 + c8 * 8);
    *(short8v*)(P_lds + row * 136 + c8 * 8) = val;
  }

  f32x4 acc[8][2];
#pragma unroll
  for (int i = 0; i < 8; ++i)
#pragma unroll
    for (int j = 0; j < 2; ++j) acc[i][j] = (f32x4){0.f, 0.f, 0.f, 0.f};

#pragma unroll
  for (int es = 0; es < 4; ++es) {
    __syncthreads();
#pragma unroll
    for (int i = 0; i < 4; ++i) {
      int idx4 = tid + i * 256;
      int s = idx4 >> 3, c4 = idx4 & 7;
      float4 x = *(const float4*)(vb + (size_t)(s0 + s) * D_ + es * 32 + c4 * 4);
      short4v h;
      h[0] = (short)f2bf(x.x); h[1] = (short)f2bf(x.y);
      h[2] = (short)f2bf(x.z); h[3] = (short)f2bf(x.w);
      *(short4v*)(V_lds + s * 36 + c4 * 4) = h;
    }
    __syncthreads();

    short8v a[8];
#pragma unroll
    for (int mt = 0; mt < 8; ++mt) {
      int d = mt * 16 + (lane & 15);
      const short* pr = P_lds + d * 136 + es * 32 + ((lane >> 4) << 2);
      a[mt] = cat8(*(const short4v*)pr, *(const short4v*)(pr + 16));
    }
#pragma unroll
    for (int nl = 0; nl < 2; ++nl) {
      int srow = (wv * 2 + nl) * 16 + (lane & 15);
      const short* vr = V_lds + srow * 36 + ((lane >> 4) << 2);
      short8v b = cat8(*(const short4v*)vr, *(const short4v*)(vr + 16));
#pragma unroll
      for (int mt = 0; mt < 8; ++mt)
        acc[mt][nl] = __builtin_amdgcn_mfma_f32_16x16x32_bf16(a[mt], b, acc[mt][nl], 0, 0, 0);
    }
  }

  float* ob = out + (size_t)bh * D_ * S_ + s0;
#pragma unroll
  for (int mt = 0; mt < 8; ++mt)
#pragma unroll
    for (int nl = 0; nl < 2; ++nl) {
      int sc = (wv * 2 + nl) * 16 + (lane & 15);
#pragma unroll
      for (int r = 0; r < 4; ++r) {
        int d = mt * 16 + ((lane >> 4) << 2) + r;
        ob[(size_t)d * S_ + sc] = acc[mt][nl][r];
      }
    }
}

extern "C" void kernel_launch(void* const* d_in, const int* in_sizes, int n_in,
                              void* d_out, int out_size, void* d_ws,
                              size_t ws_size, hipStream_t stream) {
  const float* q = (const float*)d_in[0];
  const float* k = (const float*)d_in[1];
  const float* v = (const float*)d_in[2];
  float* out = (float*)d_out;
  char* ws = (char*)d_ws;

  const size_t PART1 = (size_t)BH * D_ * D_ * sizeof(float);  // 4 MiB
  const size_t PSZ = (size_t)BH * D_ * D_ * sizeof(short);    // 2 MiB

  if (ws_size >= 16 * PART1 + PSZ) {
    float* part = (float*)ws;
    short* Pg = (short*)(ws + 16 * PART1);
    qk_mfma<false><<<dim3(BH, 16, 2), 256, 0, stream>>>(q, k, part);
    softmax_k<16><<<dim3(BH, 4), 256, 0, stream>>>(part, Pg);
    pv_mfma<<<dim3(BH, 32), 256, 0, stream>>>(Pg, v, out);
  } else {
    float* part = (float*)ws;
    short* Pg = (short*)(ws + PART1);
    hipMemsetAsync(ws, 0, PART1, stream);
    qk_mfma<true><<<dim3(BH, 16, 2), 256, 0, stream>>>(q, k, part);
    softmax_k<1><<<dim3(BH, 4), 256, 0, stream>>>(part, Pg);
    pv_mfma<<<dim3(BH, 32), 256, 0, stream>>>(Pg, v, out);
  }
}